// Round 1
// baseline (34.409 us; speedup 1.0000x reference)
//
#include <hip/hip_runtime.h>

// Problem constants (from reference setup_inputs):
//   y_pred: [B, PRED] fp32,  y_ori: [B, T] fp32,  SCALE = PRED/T = 4
#define B_ROWS 4096
#define T_LEN  2048
#define PRED_LEN 8192
#define NTHREADS 256

// Kernel 1: per-row masked MSE over detected maxima.
// One block per row. y_ori row staged in LDS; y_pred read as float4 per window.
__global__ __launch_bounds__(NTHREADS) void tsmal_row_kernel(
    const float* __restrict__ y_pred,
    const float* __restrict__ y_ori,
    float* __restrict__ ws_loss,   // [B] per-row batch_loss (0 if invalid)
    float* __restrict__ ws_valid)  // [B] 1.0 if row has any maxima else 0.0
{
    __shared__ float s_ori[T_LEN];
    const int row = blockIdx.x;
    const int tid = threadIdx.x;

    // Stage y_ori row into LDS with float4 loads (2048 floats = 512 float4).
    const float4* ori4 = reinterpret_cast<const float4*>(y_ori + (size_t)row * T_LEN);
    #pragma unroll
    for (int j = tid; j < T_LEN / 4; j += NTHREADS) {
        float4 v = ori4[j];
        s_ori[4 * j + 0] = v.x;
        s_ori[4 * j + 1] = v.y;
        s_ori[4 * j + 2] = v.z;
        s_ori[4 * j + 3] = v.w;
    }
    __syncthreads();

    const float4* pred4 = reinterpret_cast<const float4*>(y_pred + (size_t)row * PRED_LEN);

    float sum = 0.0f;
    float cnt = 0.0f;

    // Each window index i corresponds exactly to one float4 of y_pred (SCALE=4).
    #pragma unroll
    for (int i = tid; i < T_LEN; i += NTHREADS) {
        // Unconditional coalesced load keeps the access pattern regular.
        float4 p = pred4[i];
        float wm = fmaxf(fmaxf(p.x, p.y), fmaxf(p.z, p.w));

        int im1 = (i >= 1) ? i - 1 : 0;
        int ip1 = (i <= T_LEN - 2) ? i + 1 : T_LEN - 1;
        float yc = s_ori[i];
        float dm = yc - s_ori[im1];          // diff[i-1]
        float dp = s_ori[ip1] - yc;          // diff[i]
        // maxima mask, only defined for interior indices 1..T-2
        bool interior = (i >= 1) && (i <= T_LEN - 2);
        bool mask = interior && (dp * dm < 0.0f) && (dm > 0.0f);

        float d = wm - yc;
        sum += mask ? d * d : 0.0f;
        cnt += mask ? 1.0f : 0.0f;
    }

    // Wave(64) shuffle reduction, then cross-wave via LDS.
    #pragma unroll
    for (int off = 32; off > 0; off >>= 1) {
        sum += __shfl_down(sum, off, 64);
        cnt += __shfl_down(cnt, off, 64);
    }

    __shared__ float s_sum[NTHREADS / 64];
    __shared__ float s_cnt[NTHREADS / 64];
    const int wave = tid >> 6;
    const int lane = tid & 63;
    if (lane == 0) {
        s_sum[wave] = sum;
        s_cnt[wave] = cnt;
    }
    __syncthreads();

    if (tid == 0) {
        float tsum = 0.0f, tcnt = 0.0f;
        #pragma unroll
        for (int w = 0; w < NTHREADS / 64; ++w) {
            tsum += s_sum[w];
            tcnt += s_cnt[w];
        }
        bool valid = tcnt > 0.0f;
        ws_loss[row]  = valid ? tsum / tcnt : 0.0f;  // sum / max(cnt,1); cnt>0 here
        ws_valid[row] = valid ? 1.0f : 0.0f;
    }
}

// Kernel 2: reduce per-row results to the final scalar.
__global__ __launch_bounds__(NTHREADS) void tsmal_final_kernel(
    const float* __restrict__ ws_loss,
    const float* __restrict__ ws_valid,
    float* __restrict__ out)
{
    const int tid = threadIdx.x;
    float total = 0.0f, nvalid = 0.0f;
    for (int i = tid; i < B_ROWS; i += NTHREADS) {
        total  += ws_loss[i];
        nvalid += ws_valid[i];
    }
    #pragma unroll
    for (int off = 32; off > 0; off >>= 1) {
        total  += __shfl_down(total, off, 64);
        nvalid += __shfl_down(nvalid, off, 64);
    }
    __shared__ float s_tot[NTHREADS / 64];
    __shared__ float s_nv[NTHREADS / 64];
    const int wave = tid >> 6;
    const int lane = tid & 63;
    if (lane == 0) {
        s_tot[wave] = total;
        s_nv[wave]  = nvalid;
    }
    __syncthreads();
    if (tid == 0) {
        float t = 0.0f, nv = 0.0f;
        #pragma unroll
        for (int w = 0; w < NTHREADS / 64; ++w) {
            t  += s_tot[w];
            nv += s_nv[w];
        }
        out[0] = (nv > 0.0f) ? t / nv : 0.0f;
    }
}

extern "C" void kernel_launch(void* const* d_in, const int* in_sizes, int n_in,
                              void* d_out, int out_size, void* d_ws, size_t ws_size,
                              hipStream_t stream) {
    const float* y_pred = (const float*)d_in[0];
    const float* y_ori  = (const float*)d_in[1];
    float* out = (float*)d_out;

    float* ws_loss  = (float*)d_ws;
    float* ws_valid = ws_loss + B_ROWS;

    tsmal_row_kernel<<<B_ROWS, NTHREADS, 0, stream>>>(y_pred, y_ori, ws_loss, ws_valid);
    tsmal_final_kernel<<<1, NTHREADS, 0, stream>>>(ws_loss, ws_valid, out);
}